// Round 4
// baseline (480.066 us; speedup 1.0000x reference)
//
#include <hip/hip_runtime.h>

// Problem dims (fixed by setup_inputs): B=4,S=2048 -> M=8192; K=4096; N=4096; bits=4; group=128
#define KD 4096
#define ND 4096
#define GRP 32          // K / group_size = scale groups per output row
#define NT (KD / 64)    // 64 K-tiles of BK=64

typedef unsigned short u16;
typedef float   f32x4  __attribute__((ext_vector_type(4)));
typedef __bf16  bf16x8 __attribute__((ext_vector_type(8)));
typedef unsigned short u16x8 __attribute__((ext_vector_type(8)));
typedef unsigned short u16x4 __attribute__((ext_vector_type(4)));

__device__ __forceinline__ u16 f2bf(float f) {        // RNE float->bf16
  unsigned u = __float_as_uint(f);
  return (u16)((u + 0x7fffu + ((u >> 16) & 1u)) >> 16);
}

__device__ __forceinline__ void async16(const void* g, void* l) {
  // global -> LDS direct copy, 16B per lane, dest = wave-uniform base + lane*16
  __builtin_amdgcn_global_load_lds(
      (const __attribute__((address_space(1))) unsigned int*)g,
      (__attribute__((address_space(3))) unsigned int*)l, 16, 0, 0);
}

// ---------------- prepass: grid-stride, 2048 blocks ----------------
__global__ __launch_bounds__(256) void prep_kernel(
    const int* __restrict__ qw, const float* __restrict__ scale,
    const float* __restrict__ zp, u16* __restrict__ wout,
    const float4* __restrict__ x, u16x4* __restrict__ xb, int nx) {
  const int nth = gridDim.x * 256;
  const int t0 = blockIdx.x * 256 + threadIdx.x;
  for (int idx4 = t0; idx4 < ND * (KD / 32); idx4 += nth) {
    int n = idx4 >> 7;                          // 128 int4 per row
    int p4 = idx4 & 127;
    int g = p4 >> 2;                            // 4 int32 per iter, 16 int32/group
    float s = scale[n * GRP + g];
    float bz = -s * zp[n * GRP + g];            // w = q*s - s*zp
    int4 q4 = ((const int4*)qw)[idx4];
    const unsigned qv[4] = {(unsigned)q4.x, (unsigned)q4.y,
                            (unsigned)q4.z, (unsigned)q4.w};
#pragma unroll
    for (int k = 0; k < 4; ++k) {
      u16x8 hv;
#pragma unroll
      for (int i = 0; i < 8; ++i)
        hv[i] = f2bf(fmaf((float)((qv[k] >> (4 * i)) & 15u), s, bz));
      *(u16x8*)(wout + (size_t)idx4 * 32 + k * 8) = hv;
    }
  }
  for (int i = t0; i < nx; i += nth) {
    float4 v = x[i];
    u16x4 h;
    h[0] = f2bf(v.x); h[1] = f2bf(v.y); h[2] = f2bf(v.z); h[3] = f2bf(v.w);
    xb[i] = h;
  }
}

// ---------------- main GEMM: 256x256 tile, BK=64, ONE barrier per K-tile ----
// Round-4 change vs round-3 (266us, MfmaUtil 47%): the 8 phase-barriers/tile
// forced all 8 waves into lockstep, so LDS-read time (24 ds_read_b128/wave/tile
// = 192KB/CU ~= 2000cy at the 85-128 B/cy LDS ceiling) ADDED to MFMA time
// (~2480cy/SIMD) -> ~5000cy/tile, exactly the measurement. Those barriers are
// not needed for correctness: tile t reads buf[t&1] while staging writes
// buf[(t+1)&1] -- disjoint. New schedule per tile:
//   1. issue all 8 global_load_lds for tile t+1 into the OTHER buffer (full-tile
//      lead ~2400cy >> 900cy HBM latency)
//   2. straight-line 24 ds_reads + 64 MFMAs (compiler's fine-grained lgkmcnt(N)
//      handles intra-tile ordering; with no barriers the 2 waves/SIMD slide out
//      of phase so one wave's ds_reads overlap the other's MFMAs [m114])
//   3. vmcnt(0) drain + ONE s_barrier (buffer swap: t+1 visible, t&1 free)
// WAR proof: writes to buf[(t+1)&1] only after the end-of-(t-1) barrier, by
// which time all waves' reads of that buffer (tile t-1) completed.
// LDS swizzle (0-conflict verified): 16B chunk c of row r at slot c^(r&7);
// global_load_lds dest is linear, so lane l pre-fetches source chunk (l&7)^(l>>3).
// C/D: col = lane&15, row = (lane>>4)*4 + reg   [m89/m91-verified]
__global__ __launch_bounds__(512, 2) void gemm256(
    const u16* __restrict__ xb, const u16* __restrict__ wb,
    const float* __restrict__ bias, float* __restrict__ out) {
  __shared__ u16 As[2][256 * 64];
  __shared__ u16 Bs[2][256 * 64];
  const int tid = threadIdx.x;
  const int l = tid & 63, w = tid >> 6;
  const int wr = w >> 2, wc = w & 3;
  const int col = l & 15, quad = l >> 4, rsw = col & 7;
  const int lr = l >> 3, csrc = (l & 7) ^ lr;

  // bijective XCD-chunked swizzle (m204)
  const int id = blockIdx.y * gridDim.x + blockIdx.x;
  const int nwg = gridDim.x * gridDim.y;
  const int q = nwg >> 3, r = nwg & 7;
  const int xcd = id & 7, off = id >> 3;
  const int wgid = (xcd < r ? xcd * (q + 1) : r * (q + 1) + (xcd - r) * q) + off;
  const int nb = gridDim.x;
  const int m0 = (wgid / nb) * 256;
  const int n0 = (wgid % nb) * 256;

  const u16* asrc = xb + (size_t)(m0 + w * 16 + lr) * KD + csrc * 8;
  const u16* bsrc = wb + (size_t)(n0 + w * 16 + lr) * KD + csrc * 8;

#define STAGE_A(t, h)                                                      \
  do {                                                                     \
    const u16* _g = asrc + (size_t)((h) * 128) * KD + (t) * 64;            \
    u16* _l = &As[(t) & 1][((h) * 128 + w * 16) * 64];                     \
    async16(_g, _l);                                                       \
    async16(_g + (size_t)8 * KD, _l + 8 * 64);                             \
  } while (0)
#define STAGE_B(t, h)                                                      \
  do {                                                                     \
    const u16* _g = bsrc + (size_t)((h) * 128) * KD + (t) * 64;            \
    u16* _l = &Bs[(t) & 1][((h) * 128 + w * 16) * 64];                     \
    async16(_g, _l);                                                       \
    async16(_g + (size_t)8 * KD, _l + 8 * 64);                             \
  } while (0)
#define STAGE4(t) do { STAGE_B(t, 0); STAGE_B(t, 1); STAGE_A(t, 0); STAGE_A(t, 1); } while (0)
#define BAR()   __builtin_amdgcn_s_barrier()
#define SB0()   __builtin_amdgcn_sched_barrier(0)
#define LDA(Ab, i, kk) \
  (*(const bf16x8*)&(Ab)[(wr * 128 + (i) * 16 + col) * 64 + ((((kk) * 4 + quad) ^ rsw) * 8)])
#define LDB(Bb, j, kk) \
  (*(const bf16x8*)&(Bb)[(wc * 64 + (j) * 16 + col) * 64 + ((((kk) * 4 + quad) ^ rsw) * 8)])
// Whole-tile compute, straight-line, NO barriers. Quadrant order (lo/hi m-half)
// keeps register pressure bounded (a[] reused, SSA-renamed by the compiler).
#define COMPUTE(Ab, Bb)                                                    \
  do {                                                                     \
    _Pragma("unroll")                                                      \
    for (int i = 0; i < 4; ++i) { a[i][0] = LDA(Ab, i, 0); a[i][1] = LDA(Ab, i, 1); } \
    _Pragma("unroll")                                                      \
    for (int j = 0; j < 4; ++j) { b[j][0] = LDB(Bb, j, 0); b[j][1] = LDB(Bb, j, 1); } \
    _Pragma("unroll")                                                      \
    for (int kk = 0; kk < 2; ++kk)                                         \
      _Pragma("unroll")                                                    \
      for (int i = 0; i < 4; ++i)                                          \
        _Pragma("unroll")                                                  \
        for (int j = 0; j < 4; ++j)                                        \
          acc[i][j] = __builtin_amdgcn_mfma_f32_16x16x32_bf16(             \
              a[i][kk], b[j][kk], acc[i][j], 0, 0, 0);                     \
    _Pragma("unroll")                                                      \
    for (int i = 0; i < 4; ++i) { a[i][0] = LDA(Ab, i + 4, 0); a[i][1] = LDA(Ab, i + 4, 1); } \
    _Pragma("unroll")                                                      \
    for (int kk = 0; kk < 2; ++kk)                                         \
      _Pragma("unroll")                                                    \
      for (int i = 0; i < 4; ++i)                                          \
        _Pragma("unroll")                                                  \
        for (int j = 0; j < 4; ++j)                                        \
          acc[4 + i][j] = __builtin_amdgcn_mfma_f32_16x16x32_bf16(         \
              a[i][kk], b[j][kk], acc[4 + i][j], 0, 0, 0);                 \
  } while (0)
#define DRAIN() do { asm volatile("s_waitcnt vmcnt(0)"); SB0(); BAR(); } while (0)

  f32x4 acc[8][4] = {};
  bf16x8 a[4][2], b[4][2];

  // prologue: stage tile 0 into buf0, drain, barrier
  STAGE4(0);
  DRAIN();

  for (int tt = 0; tt < NT - 2; tt += 2) {
    STAGE4(tt + 1);            // -> buf1 (disjoint from buf0 being read)
    SB0();                     // pin stage-issue before the tile's ds_reads
    COMPUTE(As[0], Bs[0]);
    DRAIN();                   // tile tt+1 landed; buf0 free for rewrite
    STAGE4(tt + 2);            // -> buf0
    SB0();
    COMPUTE(As[1], Bs[1]);
    DRAIN();
  }
  // tt = NT-2: stage last tile, compute NT-2, then NT-1 (no further staging)
  STAGE4(NT - 1);              // -> buf1
  SB0();
  COMPUTE(As[0], Bs[0]);
  DRAIN();
  COMPUTE(As[1], Bs[1]);

  // epilogue: add bias, store fp32
#pragma unroll
  for (int j = 0; j < 4; ++j) {
    int n = n0 + wc * 64 + j * 16 + col;
    float bj = bias[n];
#pragma unroll
    for (int i = 0; i < 8; ++i) {
      int mrow = m0 + wr * 128 + i * 16 + quad * 4;
#pragma unroll
      for (int rr = 0; rr < 4; ++rr)
        out[(size_t)(mrow + rr) * ND + n] = acc[i][j][rr] + bj;
    }
  }
#undef STAGE_A
#undef STAGE_B
#undef STAGE4
#undef BAR
#undef SB0
#undef LDA
#undef LDB
#undef COMPUTE
#undef DRAIN
}

// ---------------- fallback GEMM (old 128x128 m97-style kernel, kept for small ws) ----
template <int XF32, int WQ>
__global__ __launch_bounds__(256, 3) void gemm_kernel(
    const u16*   __restrict__ xbp,
    const float* __restrict__ xf,
    const u16*   __restrict__ wbp,
    const int*   __restrict__ qw,
    const float* __restrict__ scale,
    const float* __restrict__ zp,
    const float* __restrict__ bias,
    float* __restrict__ out) {
  __shared__ u16 As[128 * 64];
  __shared__ u16 Bs[128 * 64];
  const int tid = threadIdx.x;
  const int l = tid & 63, w = tid >> 6;
  const int m0 = blockIdx.y * 128, n0 = blockIdx.x * 128;
  const int wm = (w >> 1) * 64, wn = (w & 1) * 64;
  const int col = l & 15, quad = l >> 4;
  const int rsw = col & 7;
  const int lr = l >> 3;
  const int csrc = (l & 7) ^ lr;
  f32x4 acc[4][4] = {};

  for (int k0 = 0; k0 < KD; k0 += 64) {
    __syncthreads();

    if constexpr (XF32) {
#pragma unroll
      for (int it = 0; it < 8; ++it) {
        int fi = it * 256 + tid;
        int row = fi >> 4, cs = fi & 15;
        float4 v = *(const float4*)(xf + (size_t)(m0 + row) * KD + k0 + cs * 4);
        u16x4 h;
        h[0] = f2bf(v.x); h[1] = f2bf(v.y); h[2] = f2bf(v.z); h[3] = f2bf(v.w);
        int slot = (cs >> 1) ^ (row & 7);
        *(u16x4*)(&As[row * 64 + slot * 8 + (cs & 1) * 4]) = h;
      }
    } else {
#pragma unroll
      for (int c = 0; c < 4; ++c) {
        int br = w * 32 + c * 8;
        const u16* g = xbp + (size_t)(m0 + br + lr) * KD + k0 + csrc * 8;
        async16(g, &As[br * 64]);
      }
    }

    if constexpr (WQ) {
#pragma unroll
      for (int it = 0; it < 4; ++it) {
        int qi = it * 256 + tid;
        int row = qi >> 3, p8 = qi & 7;
        int nrow = n0 + row;
        int g = k0 >> 7;
        float s = scale[nrow * GRP + g];
        float bz = -s * zp[nrow * GRP + g];
        unsigned qv = (unsigned)qw[(size_t)nrow * (KD / 8) + (k0 >> 3) + p8];
        u16x8 hv;
#pragma unroll
        for (int i = 0; i < 8; ++i)
          hv[i] = f2bf(fmaf((float)((qv >> (4 * i)) & 15u), s, bz));
        *(u16x8*)(&Bs[row * 64 + ((p8 ^ (row & 7)) * 8)]) = hv;
      }
    } else {
#pragma unroll
      for (int c = 0; c < 4; ++c) {
        int br = w * 32 + c * 8;
        const u16* g = wbp + (size_t)(n0 + br + lr) * KD + k0 + csrc * 8;
        async16(g, &Bs[br * 64]);
      }
    }

    __syncthreads();

#pragma unroll
    for (int kk = 0; kk < 2; ++kk) {
      bf16x8 a[4], b[4];
      const int slot = ((kk * 4 + quad) ^ rsw) * 8;
#pragma unroll
      for (int i = 0; i < 4; ++i)
        a[i] = *(const bf16x8*)&As[(wm + i * 16 + col) * 64 + slot];
#pragma unroll
      for (int j = 0; j < 4; ++j)
        b[j] = *(const bf16x8*)&Bs[(wn + j * 16 + col) * 64 + slot];
#pragma unroll
      for (int i = 0; i < 4; ++i)
#pragma unroll
        for (int j = 0; j < 4; ++j)
          acc[i][j] = __builtin_amdgcn_mfma_f32_16x16x32_bf16(a[i], b[j], acc[i][j], 0, 0, 0);
    }
  }

#pragma unroll
  for (int j = 0; j < 4; ++j) {
    int n = n0 + wn + j * 16 + col;
    float bj = bias[n];
#pragma unroll
    for (int i = 0; i < 4; ++i) {
      int mrow = m0 + wm + i * 16 + quad * 4;
#pragma unroll
      for (int rr = 0; rr < 4; ++rr)
        out[(size_t)(mrow + rr) * ND + n] = acc[i][j][rr] + bj;
    }
  }
}

extern "C" void kernel_launch(void* const* d_in, const int* in_sizes, int n_in,
                              void* d_out, int out_size, void* d_ws, size_t ws_size,
                              hipStream_t stream) {
  const float* x     = (const float*)d_in[0];
  const int*   qw    = (const int*)d_in[1];
  const float* scale = (const float*)d_in[2];
  const float* zp    = (const float*)d_in[3];
  const float* bias  = (const float*)d_in[4];
  float* out = (float*)d_out;

  const int M = in_sizes[0] / KD;  // 8192

  const size_t needW = (size_t)ND * KD * sizeof(u16);  // 32 MB
  const size_t needX = (size_t)M * KD * sizeof(u16);   // 64 MB

  if (ws_size >= needW + needX && (M % 256) == 0) {
    u16* wb = (u16*)d_ws;
    u16* xbuf = wb + (size_t)ND * KD;
    prep_kernel<<<2048, 256, 0, stream>>>(qw, scale, zp, wb,
                                          (const float4*)x, (u16x4*)xbuf,
                                          M * (KD / 4));
    dim3 grid(ND / 256, M / 256);
    gemm256<<<grid, dim3(512), 0, stream>>>(xbuf, wb, bias, out);
  } else if (ws_size >= needW) {
    u16* wb = (u16*)d_ws;
    prep_kernel<<<2048, 256, 0, stream>>>(qw, scale, zp, wb, nullptr, nullptr, 0);
    dim3 grid(ND / 128, M / 128);
    gemm_kernel<1, 0><<<grid, dim3(256), 0, stream>>>(nullptr, x, wb, qw, scale, zp, bias, out);
  } else {
    dim3 grid(ND / 128, M / 128);
    gemm_kernel<1, 1><<<grid, dim3(256), 0, stream>>>(nullptr, x, nullptr, qw, scale, zp, bias, out);
  }
}